// Round 9
// baseline (5739.886 us; speedup 1.0000x reference)
//
#include <hip/hip_runtime.h>

#define NTAG 48
#define SEQ 1024
#define NBATCH 512
#define CH 128                    // steps (rows) per LDS chunk
#define NCH (SEQ / CH)            // 8
#define CHF (CH * NTAG)           // 6144 floats per chunk
#define NISS (CHF * 4 / 1024)     // 24 global_load_lds issues per chunk (1KB each)
#define NEG_INF (-3.402823466e+38f)

// broadcast lane `lane`'s value of v to all lanes (compile-time lane -> v_readlane imm)
__device__ __forceinline__ float rl_f32(float v, int lane) {
    return __int_as_float(__builtin_amdgcn_readlane(__float_as_int(v), lane));
}

// async global->LDS, 16B per lane; LDS dest = base + lane*16 (linear), global src per-lane
#define GLDS16(gp, lp)                                                                   \
    __builtin_amdgcn_global_load_lds((const __attribute__((address_space(1))) void*)(gp),\
                                     (__attribute__((address_space(3))) void*)(lp),      \
                                     16, 0, 0)

__global__ __launch_bounds__(64, 1) void crf_viterbi_kernel(
    const float* __restrict__ em,      // [B, S, T]
    const float* __restrict__ trans,   // [T, T]
    const float* __restrict__ start,   // [T]
    const float* __restrict__ endt,    // [T]
    int* __restrict__ out,             // [B, S] tags (int32)
    unsigned char* __restrict__ bp)    // [B, S, T] backpointers (workspace)
{
    const int b  = blockIdx.x;
    const int j  = threadIdx.x;                 // 0..63; tags 0..47 valid
    const int jj = (j < NTAG) ? j : (NTAG - 1); // clamped for safe loads

    __shared__ float stage[2][CHF];     // 2 x 24KB em staging
    __shared__ int obuf[SEQ];

    // transition column j in regs: trg[i] = T[i][j]
    float trg[NTAG];
#pragma unroll
    for (int i = 0; i < NTAG; ++i) trg[i] = trans[i * NTAG + jj];

    const float* emb = em + (size_t)b * SEQ * NTAG;
    unsigned char* bpb = bp + (size_t)b * SEQ * NTAG;

    // ---- prologue: stage em chunk 0 ----
#pragma unroll
    for (int k = 0; k < NISS; ++k)
        GLDS16(emb + k * 256 + j * 4, &stage[0][k * 256]);
    asm volatile("s_waitcnt vmcnt(0)" ::: "memory");

    float score = start[jj] + stage[0][jj];     // S_0[j]

    // ---------------- forward: lane-parallel value+index argmax ----------------
    int cb = 0;
    for (int c = 0; c < NCH; ++c) {
        if (c + 1 < NCH) {
            const float* gs = emb + (size_t)(c + 1) * CHF;
#pragma unroll
            for (int k = 0; k < NISS; ++k)
                GLDS16(gs + k * 256 + j * 4, &stage[cb ^ 1][k * 256]);
        }
        const int tt0 = (c == 0) ? 1 : 0;
        for (int tt = tt0; tt < CH; ++tt) {
            float em_j = stage[cb][tt * NTAG + jj];

            // leaves: cand_i = S_{t-1}[i] + T[i][j]  (exact ref fp order)
            float val[NTAG];
#pragma unroll
            for (int i = 0; i < NTAG; ++i)
                val[i] = rl_f32(score, i) + trg[i];

            // pairwise value+index tree; '>=' picks LEFT on ties and adjacent
            // pairing keeps ascending index order => exact first-max (jnp.argmax)
            float v24[24]; int i24[24];
#pragma unroll
            for (int k = 0; k < 24; ++k) {
                bool ge = val[2 * k] >= val[2 * k + 1];
                v24[k] = fmaxf(val[2 * k], val[2 * k + 1]);
                i24[k] = ge ? (2 * k) : (2 * k + 1);
            }
            float v12[12]; int i12[12];
#pragma unroll
            for (int k = 0; k < 12; ++k) {
                bool ge = v24[2 * k] >= v24[2 * k + 1];
                v12[k] = fmaxf(v24[2 * k], v24[2 * k + 1]);
                i12[k] = ge ? i24[2 * k] : i24[2 * k + 1];
            }
            float v6[6]; int i6[6];
#pragma unroll
            for (int k = 0; k < 6; ++k) {
                bool ge = v12[2 * k] >= v12[2 * k + 1];
                v6[k] = fmaxf(v12[2 * k], v12[2 * k + 1]);
                i6[k] = ge ? i12[2 * k] : i12[2 * k + 1];
            }
            float v3[3]; int i3[3];
#pragma unroll
            for (int k = 0; k < 3; ++k) {
                bool ge = v6[2 * k] >= v6[2 * k + 1];
                v3[k] = fmaxf(v6[2 * k], v6[2 * k + 1]);
                i3[k] = ge ? i6[2 * k] : i6[2 * k + 1];
            }
            bool geA = v3[0] >= v3[1];
            float vA  = fmaxf(v3[0], v3[1]);
            int   iA  = geA ? i3[0] : i3[1];
            bool geB = vA >= v3[2];
            float best = fmaxf(vA, v3[2]);
            int   pi   = geB ? iA : i3[2];

            int t = c * CH + tt;
            if (j < NTAG) bpb[(size_t)t * NTAG + j] = (unsigned char)pi;
            score = best + em_j;                 // S_t[j], exact ref order
        }
        asm volatile("s_waitcnt vmcnt(0)" ::: "memory");  // next chunk staged + bp drained
        cb ^= 1;
    }

    // ---------------- final tag: argmax_j(S_{S-1}[j] + end[j]) ----------------
    float fs = (j < NTAG) ? (score + endt[jj]) : NEG_INF;
    float mx = fs;
    mx = fmaxf(mx, __shfl_xor(mx, 32, 64));
    mx = fmaxf(mx, __shfl_xor(mx, 16, 64));
    mx = fmaxf(mx, __shfl_xor(mx,  8, 64));
    mx = fmaxf(mx, __shfl_xor(mx,  4, 64));
    mx = fmaxf(mx, __shfl_xor(mx,  2, 64));
    mx = fmaxf(mx, __shfl_xor(mx,  1, 64));
    unsigned long long bl = __ballot(fs == mx);
    int tag = __ffsll(bl) - 1;                   // first-max (lowest j), exact; uniform

    if (j == 0) obuf[SEQ - 1] = tag;

    // ---------------- backtrace: uniform readlane chain (~10 cyc/step) ----------------
    // rows prefetched 16-deep lane-parallel; tag_{t-1} = bp_row_t[tag_t] via v_readlane
    int cur[16], nxt[16];
    int t = SEQ - 1;
    int n = 16;                                  // t = 1023 >= 16
#pragma unroll
    for (int k = 0; k < 16; ++k)
        cur[k] = (int)bpb[(size_t)(t - k) * NTAG + jj];

    while (t >= 1) {
        int t2 = t - n;
        int n2 = 0;
        if (t2 >= 1) {
            n2 = (t2 >= 16) ? 16 : t2;
#pragma unroll
            for (int k = 0; k < 16; ++k)
                if (k < n2) nxt[k] = (int)bpb[(size_t)(t2 - k) * NTAG + jj];
        }
#pragma unroll
        for (int k = 0; k < 16; ++k) {
            if (k < n) {
                tag = __builtin_amdgcn_readlane(cur[k], tag);  // uniform scalar chase
                if (j == 0) obuf[t - k - 1] = tag;
            }
        }
#pragma unroll
        for (int k = 0; k < 16; ++k) cur[k] = nxt[k];
        t = t2; n = n2;
    }

    __syncthreads();

    // coalesced int32 dump of the batch's path
    int* outb = out + (size_t)b * SEQ;
#pragma unroll
    for (int t0 = 0; t0 < SEQ / 64; ++t0)
        outb[t0 * 64 + j] = obuf[t0 * 64 + j];
}

extern "C" void kernel_launch(void* const* d_in, const int* in_sizes, int n_in,
                              void* d_out, int out_size, void* d_ws, size_t ws_size,
                              hipStream_t stream) {
    const float* em    = (const float*)d_in[0];
    // d_in[1] = mask (int32), unused — matches reference
    const float* trans = (const float*)d_in[2];
    const float* start = (const float*)d_in[3];
    const float* endt  = (const float*)d_in[4];
    int* out = (int*)d_out;
    unsigned char* bpw = (unsigned char*)d_ws;  // needs B*S*T = 25,165,824 bytes

    crf_viterbi_kernel<<<NBATCH, 64, 0, stream>>>(em, trans, start, endt, out, bpw);
}

// Round 10
// 1023.816 us; speedup vs baseline: 5.6064x; 5.6064x over previous
//
#include <hip/hip_runtime.h>

#define NTAG 48
#define SEQ 1024
#define NBATCH 512
#define CH 128                    // steps (rows) per LDS chunk
#define NCH (SEQ / CH)            // 8
#define CHF (CH * NTAG)           // 6144 floats per chunk
#define NISS (CHF * 4 / 1024)     // 24 global_load_lds issues per chunk (1KB each)
#define NEG_INF (-3.402823466e+38f)

// broadcast lane `lane`'s value of v to all lanes (compile-time lane -> v_readlane imm)
__device__ __forceinline__ float rl_f32(float v, int lane) {
    return __int_as_float(__builtin_amdgcn_readlane(__float_as_int(v), lane));
}

// single-instruction 3-input max (exact; max has no rounding)
__device__ __forceinline__ float max3(float a, float b, float c) {
    float d;
    asm("v_max3_f32 %0, %1, %2, %3" : "=v"(d) : "v"(a), "v"(b), "v"(c));
    return d;
}

// async global->LDS, 16B per lane; LDS dest = base + lane*16 (linear), global src per-lane
#define GLDS16(gp, lp)                                                                   \
    __builtin_amdgcn_global_load_lds((const __attribute__((address_space(1))) void*)(gp),\
                                     (__attribute__((address_space(3))) void*)(lp),      \
                                     16, 0, 0)

__global__ __launch_bounds__(64, 1) void crf_viterbi_kernel(
    const float* __restrict__ em,      // [B, S, T]
    const float* __restrict__ trans,   // [T, T]
    const float* __restrict__ start,   // [T]
    const float* __restrict__ endt,    // [T]
    int* __restrict__ out,             // [B, S] tags (int32)
    unsigned char* __restrict__ bp)    // [B, S, T] backpointers (workspace)
{
    const int b  = blockIdx.x;
    const int j  = threadIdx.x;                 // 0..63; tags 0..47 valid
    const int jj = (j < NTAG) ? j : (NTAG - 1); // clamped for safe loads

    __shared__ float stage[2][CHF];     // 2 x 24KB em staging
    __shared__ int obuf[SEQ];

    // transition column j in regs: trg[i] = T[i][j]
    float trg[NTAG];
#pragma unroll
    for (int i = 0; i < NTAG; ++i) trg[i] = trans[i * NTAG + jj];

    const float* emb = em + (size_t)b * SEQ * NTAG;
    unsigned char* bpb = bp + (size_t)b * SEQ * NTAG;

    // ---- prologue: stage em chunk 0 ----
#pragma unroll
    for (int k = 0; k < NISS; ++k)
        GLDS16(emb + k * 256 + j * 4, &stage[0][k * 256]);
    asm volatile("s_waitcnt vmcnt(0)" ::: "memory");

    float score = start[jj] + stage[0][jj];     // S_0[j]

    // ---------------- forward: R5-proven body (VGPR=56, no spills) ----------------
    int cb = 0;
    for (int c = 0; c < NCH; ++c) {
        if (c + 1 < NCH) {
            const float* gs = emb + (size_t)(c + 1) * CHF;
#pragma unroll
            for (int k = 0; k < NISS; ++k)
                GLDS16(gs + k * 256 + j * 4, &stage[cb ^ 1][k * 256]);
        }
        const int tt0 = (c == 0) ? 1 : 0;
        for (int tt = tt0; tt < CH; ++tt) {
            float em_j = stage[cb][tt * NTAG + jj];

            // candidates (exact ref fp order: s[i] + T[i][j])
            float cand[NTAG];
#pragma unroll
            for (int i = 0; i < NTAG; ++i)
                cand[i] = rl_f32(score, i) + trg[i];

            // exact max via max3 tree: 48 -> 16 -> 6 -> 2 -> 1  (24 ops)
            float l1[16];
#pragma unroll
            for (int k = 0; k < 16; ++k)
                l1[k] = max3(cand[3 * k], cand[3 * k + 1], cand[3 * k + 2]);
            float l2[6];
            l2[0] = max3(l1[0],  l1[1],  l1[2]);
            l2[1] = max3(l1[3],  l1[4],  l1[5]);
            l2[2] = max3(l1[6],  l1[7],  l1[8]);
            l2[3] = max3(l1[9],  l1[10], l1[11]);
            l2[4] = max3(l1[12], l1[13], l1[14]);
            l2[5] = l1[15];
            float m0 = max3(l2[0], l2[1], l2[2]);
            float m1 = max3(l2[3], l2[4], l2[5]);
            float best = fmaxf(m0, m1);

            // first-max index: descending equality scan, VCC consumed immediately
            // (ties -> smallest i; exact vs jnp.argmax since fp max is exact)
            int pi = 0;
#pragma unroll
            for (int i = NTAG - 1; i >= 0; --i)
                pi = (cand[i] == best) ? i : pi;

            int t = c * CH + tt;
            if (j < NTAG) bpb[(size_t)t * NTAG + j] = (unsigned char)pi;
            score = best + em_j;                 // S_t[j], exact ref order
        }
        asm volatile("s_waitcnt vmcnt(0)" ::: "memory");  // next chunk staged + bp drained
        cb ^= 1;
    }

    // ---------------- final tag: argmax_j(S_{S-1}[j] + end[j]) ----------------
    float fs = (j < NTAG) ? (score + endt[jj]) : NEG_INF;
    float mx = fs;
    mx = fmaxf(mx, __shfl_xor(mx, 32, 64));
    mx = fmaxf(mx, __shfl_xor(mx, 16, 64));
    mx = fmaxf(mx, __shfl_xor(mx,  8, 64));
    mx = fmaxf(mx, __shfl_xor(mx,  4, 64));
    mx = fmaxf(mx, __shfl_xor(mx,  2, 64));
    mx = fmaxf(mx, __shfl_xor(mx,  1, 64));
    unsigned long long bl = __ballot(fs == mx);
    int tag = __ffsll(bl) - 1;                   // first-max (lowest j), exact; uniform

    if (j == 0) obuf[SEQ - 1] = tag;

    // ---------------- backtrace: uniform readlane chain (R9-proven, ~10µs) ----------------
    int cur[16], nxt[16];
    int t = SEQ - 1;
    int n = 16;                                  // t = 1023 >= 16
#pragma unroll
    for (int k = 0; k < 16; ++k)
        cur[k] = (int)bpb[(size_t)(t - k) * NTAG + jj];

    while (t >= 1) {
        int t2 = t - n;
        int n2 = 0;
        if (t2 >= 1) {
            n2 = (t2 >= 16) ? 16 : t2;
#pragma unroll
            for (int k = 0; k < 16; ++k)
                if (k < n2) nxt[k] = (int)bpb[(size_t)(t2 - k) * NTAG + jj];
        }
#pragma unroll
        for (int k = 0; k < 16; ++k) {
            if (k < n) {
                tag = __builtin_amdgcn_readlane(cur[k], tag);  // uniform scalar chase
                if (j == 0) obuf[t - k - 1] = tag;
            }
        }
#pragma unroll
        for (int k = 0; k < 16; ++k) cur[k] = nxt[k];
        t = t2; n = n2;
    }

    __syncthreads();

    // coalesced int32 dump of the batch's path
    int* outb = out + (size_t)b * SEQ;
#pragma unroll
    for (int t0 = 0; t0 < SEQ / 64; ++t0)
        outb[t0 * 64 + j] = obuf[t0 * 64 + j];
}

extern "C" void kernel_launch(void* const* d_in, const int* in_sizes, int n_in,
                              void* d_out, int out_size, void* d_ws, size_t ws_size,
                              hipStream_t stream) {
    const float* em    = (const float*)d_in[0];
    // d_in[1] = mask (int32), unused — matches reference
    const float* trans = (const float*)d_in[2];
    const float* start = (const float*)d_in[3];
    const float* endt  = (const float*)d_in[4];
    int* out = (int*)d_out;
    unsigned char* bpw = (unsigned char*)d_ws;  // needs B*S*T = 25,165,824 bytes

    crf_viterbi_kernel<<<NBATCH, 64, 0, stream>>>(em, trans, start, endt, out, bpw);
}

// Round 12
// 830.336 us; speedup vs baseline: 6.9127x; 1.2330x over previous
//
#include <hip/hip_runtime.h>

#define NTAG 48
#define SEQ 1024
#define NBATCH 512
#define CH 128                    // steps per LDS chunk
#define NCH (SEQ / CH)            // 8
#define CHF (CH * NTAG)           // 6144 floats per chunk
#define NISS (CHF / 1024)         // 6 global_load_lds issues/chunk (256 thr x 16B)
#define QW 12                     // source tags per wave
#define NEG_INF (-3.402823466e+38f)

__device__ __forceinline__ float rl_f32(float v, int lane) {
    return __int_as_float(__builtin_amdgcn_readlane(__float_as_int(v), lane));
}

// single-instruction 3-input max (exact)
__device__ __forceinline__ float max3(float a, float b, float c) {
    float d;
    asm("v_max3_f32 %0, %1, %2, %3" : "=v"(d) : "v"(a), "v"(b), "v"(c));
    return d;
}

#define GLDS16(gp, lp)                                                                   \
    __builtin_amdgcn_global_load_lds((const __attribute__((address_space(1))) void*)(gp),\
                                     (__attribute__((address_space(3))) void*)(lp),      \
                                     16, 0, 0)

// barrier with LDS-only drain (no vmcnt: keep prefetch/stores in flight)
#define BAR_LGKM() do {                                            \
    asm volatile("s_waitcnt lgkmcnt(0)" ::: "memory");             \
    __builtin_amdgcn_s_barrier();                                  \
    asm volatile("" ::: "memory");                                 \
} while (0)

// full drain barrier (chunk boundaries)
#define BAR_ALL() do {                                             \
    asm volatile("s_waitcnt vmcnt(0) lgkmcnt(0)" ::: "memory");    \
    __builtin_amdgcn_s_barrier();                                  \
    asm volatile("" ::: "memory");                                 \
} while (0)

__global__ __launch_bounds__(256, 1) void crf_viterbi_kernel(
    const float* __restrict__ em,      // [B, S, T]
    const float* __restrict__ trans,   // [T, T]
    const float* __restrict__ start,   // [T]
    const float* __restrict__ endt,    // [T]
    int* __restrict__ out,             // [B, S] tags (int32)
    unsigned char* __restrict__ bp)    // [B, S, T] backpointers (workspace)
{
    const int b     = blockIdx.x;
    const int tid   = threadIdx.x;
    const int w     = tid >> 6;                  // wave 0..3, owns i in [12w,12w+12)
    const int j     = tid & 63;                  // lane = target tag
    const int jj    = (j < NTAG) ? j : (NTAG - 1);
    const int wbase = w * QW;

    __shared__ float stage[2][CHF];      // 2 x 24KB em staging
    __shared__ float pval[2][4][NTAG];   // per-step partial maxes (parity dbuf)
    __shared__ int   pidx[2][4][NTAG];   // per-step partial first-max indices
    __shared__ int   obuf[SEQ];

    // wave w's slice of the transition column j: trgq[k] = T[wbase+k][j]
    float trgq[QW];
#pragma unroll
    for (int k = 0; k < QW; ++k) trgq[k] = trans[(wbase + k) * NTAG + jj];

    const float* emb = em + (size_t)b * SEQ * NTAG;
    unsigned char* bpb = bp + (size_t)b * SEQ * NTAG;

    // ---- prologue: all 4 waves cooperatively stage em chunk 0 ----
#pragma unroll
    for (int k = 0; k < NISS; ++k)
        GLDS16(emb + k * 1024 + tid * 4, &stage[0][k * 1024 + (w << 8)]);
    BAR_ALL();

    float score = start[jj] + stage[0][jj];      // S_0[j] (identical in all waves)

    // ---------------- forward: 4-wave i-split, one barrier/step ----------------
    int cb = 0, pb = 0;
    for (int c = 0; c < NCH; ++c) {
        if (c + 1 < NCH) {
            const float* gs = emb + (size_t)(c + 1) * CHF;
#pragma unroll
            for (int k = 0; k < NISS; ++k)
                GLDS16(gs + k * 1024 + tid * 4, &stage[cb ^ 1][k * 1024 + (w << 8)]);
        }
        const int tt0 = (c == 0) ? 1 : 0;
        for (int tt = tt0; tt < CH; ++tt) {
            float em_j = stage[cb][tt * NTAG + jj];

            // quarter candidates (exact ref fp order: s[i] + T[i][j])
            float cd[QW];
#pragma unroll
            for (int i = 0; i < QW; ++i)
                cd[i] = rl_f32(score, wbase + i) + trgq[i];

            // quarter max (exact) via max3 tree: 12 -> 4 -> 1
            float m0 = max3(cd[0], cd[1],  cd[2]);
            float m1 = max3(cd[3], cd[4],  cd[5]);
            float m2 = max3(cd[6], cd[7],  cd[8]);
            float m3 = max3(cd[9], cd[10], cd[11]);
            float qv = fmaxf(max3(m0, m1, m2), m3);

            // first-max within quarter: descending equality scan (12 deep)
            int qi = 0;
#pragma unroll
            for (int i = QW - 1; i >= 0; --i)
                qi = (cd[i] == qv) ? i : qi;

            if (j < NTAG) {
                pval[pb][w][j] = qv;
                pidx[pb][w][j] = wbase + qi;
            }
            BAR_LGKM();

            // combine quarters (all waves, value-only; exact max-of-maxes)
            float q0 = pval[pb][0][jj];
            float q1 = pval[pb][1][jj];
            float q2 = pval[pb][2][jj];
            float q3 = pval[pb][3][jj];
            float best = fmaxf(fmaxf(q0, q1), fmaxf(q2, q3));

            // backpointer: quarter-ordered first-max; duty rotates across waves
            if (w == (tt & 3) && j < NTAG) {
                int i0 = pidx[pb][0][j], i1 = pidx[pb][1][j];
                int i2 = pidx[pb][2][j], i3 = pidx[pb][3][j];
                int pi = (q0 == best) ? i0
                       : (q1 == best) ? i1
                       : (q2 == best) ? i2 : i3;
                int t = c * CH + tt;
                bpb[(size_t)t * NTAG + j] = (unsigned char)pi;
            }
            score = best + em_j;                 // S_t[j], exact ref order
            pb ^= 1;
        }
        BAR_ALL();   // all waves' chunk prefetch + bp stores drained
        cb ^= 1;
    }

    // ---------------- final tag + backtrace (wave 0 only) ----------------
    if (w == 0) {
        float fs = (j < NTAG) ? (score + endt[jj]) : NEG_INF;
        float mx = fs;
        mx = fmaxf(mx, __shfl_xor(mx, 32, 64));
        mx = fmaxf(mx, __shfl_xor(mx, 16, 64));
        mx = fmaxf(mx, __shfl_xor(mx,  8, 64));
        mx = fmaxf(mx, __shfl_xor(mx,  4, 64));
        mx = fmaxf(mx, __shfl_xor(mx,  2, 64));
        mx = fmaxf(mx, __shfl_xor(mx,  1, 64));
        unsigned long long bl = __ballot(fs == mx);
        int tag = __ffsll(bl) - 1;               // first-max (lowest j); uniform

        if (j == 0) obuf[SEQ - 1] = tag;

        // uniform readlane chase, rows prefetched 16-deep lane-parallel
        int cur[16], nxt[16];
        int t = SEQ - 1;
        int n = 16;
#pragma unroll
        for (int k = 0; k < 16; ++k)
            cur[k] = (int)bpb[(size_t)(t - k) * NTAG + jj];

        while (t >= 1) {
            int t2 = t - n;
            int n2 = 0;
            if (t2 >= 1) {
                n2 = (t2 >= 16) ? 16 : t2;
#pragma unroll
                for (int k = 0; k < 16; ++k)
                    if (k < n2) nxt[k] = (int)bpb[(size_t)(t2 - k) * NTAG + jj];
            }
#pragma unroll
            for (int k = 0; k < 16; ++k) {
                if (k < n) {
                    tag = __builtin_amdgcn_readlane(cur[k], tag);
                    if (j == 0) obuf[t - k - 1] = tag;
                }
            }
#pragma unroll
            for (int k = 0; k < 16; ++k) cur[k] = nxt[k];
            t = t2; n = n2;
        }
    }

    __syncthreads();

    // coalesced int32 dump of the batch's path (256 threads x 4)
    int* outb = out + (size_t)b * SEQ;
#pragma unroll
    for (int k = 0; k < SEQ / 256; ++k)
        outb[k * 256 + tid] = obuf[k * 256 + tid];
}

extern "C" void kernel_launch(void* const* d_in, const int* in_sizes, int n_in,
                              void* d_out, int out_size, void* d_ws, size_t ws_size,
                              hipStream_t stream) {
    const float* em    = (const float*)d_in[0];
    // d_in[1] = mask (int32), unused — matches reference
    const float* trans = (const float*)d_in[2];
    const float* start = (const float*)d_in[3];
    const float* endt  = (const float*)d_in[4];
    int* out = (int*)d_out;
    unsigned char* bpw = (unsigned char*)d_ws;  // needs B*S*T = 25,165,824 bytes

    crf_viterbi_kernel<<<NBATCH, 256, 0, stream>>>(em, trans, start, endt, out, bpw);
}